// Round 8
// baseline (814.455 us; speedup 1.0000x reference)
//
#include <hip/hip_runtime.h>

// Problem constants (match reference setup_inputs / module constants)
#define EPS_F      1e-4f
#define GRID_RES_F 0.01f
#define ATOL_F     0.01f
#define RTOL_F     1e-5f

static constexpr int V = 1200;
static constexpr int E = 4800;
static constexpr int S = V + E;      // 6000 filtration points
static constexpr int P = 2500;
static constexpr int R = 3;

static constexpr int NROWS      = 2 * R * P;   // 15000 G rows, address-ordered
static constexpr int F4_PER_ROW = 3000;        // 12000 floats / 4
static constexpr unsigned Q4    = (unsigned)NROWS * F4_PER_ROW;  // 45,000,000 float4 stores

static constexpr int NBLK = 2048, BS = 256;    // 8 blocks/CU, persistent grid-stride

// Output layout (flat fp32, return order):
//   bars0: [0, 7500)   bars1: [7500, 15000)
//   G0: (R,P,2S) at 15000   G1: follows   Gc0: (R,P,2)   Gc1: follows
// G0|G1 together are NROWS contiguous rows: row rid = b*R*P + r*P + p.
static constexpr size_t G0_BASE  = 15000ull;   // %4==0 -> float4-aligned
static constexpr size_t ROW_LEN  = 2ull * S;   // 12000 floats
static constexpr size_t G_ELEMS  = (size_t)R * P * ROW_LEN;
static constexpr size_t GC0_BASE = G0_BASE + 2 * G_ELEMS;   // 180,015,000; Gc[rid] at +2*rid

// ---------------------------------------------------------------------------
// Kernel 1: build filtration table filt[j] = (fx, fy, tol_x, tol_y); also
// zeroes the per-row flag array (avoids an extra memset launch).
// ---------------------------------------------------------------------------
__global__ void build_filt_kernel(const float* __restrict__ f_v,
                                  const int*   __restrict__ edges,
                                  float4*      __restrict__ filt,
                                  int*         __restrict__ flags) {
    int j = blockIdx.x * blockDim.x + threadIdx.x;
    if (j < NROWS) flags[j] = 0;
    if (j >= S) return;
    float fx, fy;
    if (j < V) {
        fx = f_v[2 * j];
        fy = f_v[2 * j + 1];
    } else {
        int e = j - V;
        int a = edges[2 * e];
        int b = edges[2 * e + 1];
        fx = __fadd_rn(fmaxf(f_v[2 * a],     f_v[2 * b]),     EPS_F);
        fy = __fadd_rn(fmaxf(f_v[2 * a + 1], f_v[2 * b + 1]), EPS_F);
    }
    // tol = ATOL + RTOL*|f| with NumPy per-op rounding (no fma contraction).
    float tolx = __fadd_rn(ATOL_F, __fmul_rn(RTOL_F, fabsf(fx)));
    float toly = __fadd_rn(ATOL_F, __fmul_rn(RTOL_F, fabsf(fy)));
    filt[j] = make_float4(fx, fy, tolx, toly);
}

// ---------------------------------------------------------------------------
// min_k |l[k] - f| ; comparing vs tol is bit-exact-equivalent to
// any_k(|l[k]-f| <= tol) — min/cmp involve no rounding. Subs keep ref rounding.
// (Field-proven: absmax 0.0.)
// ---------------------------------------------------------------------------
__device__ __forceinline__ float mindist(const float* l, float f) {
    float a = fabsf(__fsub_rn(l[0], f));
    float b = fabsf(__fsub_rn(l[1], f));
    float c = fabsf(__fsub_rn(l[2], f));
    float d = fabsf(__fsub_rn(l[3], f));
    float e = fabsf(__fsub_rn(l[4], f));
    return fminf(fminf(fminf(a, b), fminf(c, d)), e);  // -> v_min3 pairs
}

__device__ __forceinline__ void cell(const float4& f, float psum,
                                     const float* lxs, const float* lys,
                                     float& vx, float& vy,
                                     int& aux, int& alx, int& auy, int& aly) {
    float fsum = __fadd_rn(f.x, f.y);
    bool ab = fsum > psum, be = fsum < psum;
    float sg = ab ? 1.0f : (be ? -1.0f : 0.0f);
    bool cx = (mindist(lxs, f.x) <= f.z) && (f.y <= lys[4]);
    bool cy = (mindist(lys, f.y) <= f.w) && (f.x <= lxs[4]);
    vx = cx ? sg : 0.0f;   // vx = ux - lx == condx ? (above - below) : 0
    vy = cy ? sg : 0.0f;
    aux |= (int)(cx && ab); alx |= (int)(cx && be);
    auy |= (int)(cy && ab); aly |= (int)(cy && be);
}

// ---------------------------------------------------------------------------
// Kernel 2: FILL-SHAPED writer. Persistent grid (2048x256) grid-strides over
// the G float4-index space q in pure ascending address order — all waves form
// ONE dense moving write front (like the 6.27 TB/s fill), instead of ~2048
// stream-heads phase-scattered over >=90MB (R0/R4/R6/R7: at any instant
// ~2048 distinct 2KB DRAM pages outstanding -> row-buffer thrash; the one
// store-path axis not yet tested). Compute derives (row, cell) from q;
// cell()/line numerics bit-identical. Row-any flags via per-wave __any +
// atomicOr (active-lane counts are exact wave multiples: 45M%64==0,
// stride%64==0); tiny epilogue writes Gc.
// ---------------------------------------------------------------------------
__global__ __launch_bounds__(256) void grad_kernel(
        const float4* __restrict__ filt,
        const float*  __restrict__ bars0,
        const float*  __restrict__ bars1,
        const float*  __restrict__ sample_pts,
        float*        __restrict__ d_out,
        int*          __restrict__ flags) {
    const unsigned stride = (unsigned)NBLK * BS;          // 524,288
    for (unsigned q = blockIdx.x * (unsigned)BS + threadIdx.x; q < Q4;
         q += stride) {
        // q -> (rid, w): row id and float4-within-row (constant u32 divides
        // -> magic-mul). float4 w covers cells 2w, 2w+1 of the row.
        const unsigned rid = q / (unsigned)F4_PER_ROW;
        const unsigned w   = q - rid * (unsigned)F4_PER_ROW;
        const unsigned b   = rid / (unsigned)(R * P);
        const unsigned rem = rid - b * (unsigned)(R * P);
        const unsigned r   = rem / (unsigned)P;
        const unsigned p   = rem - r * (unsigned)P;

        const float* bar = b ? bars1 : bars0;
        const float px = sample_pts[2 * p];
        const float py = sample_pts[2 * p + 1];
        const float psum = __fadd_rn(px, py);
        const float s  = __fadd_rn(bar[p * R + r], GRID_RES_F);
        const float s2 = __fmul_rn(2.0f, s);   // exact (x2)

        float lxs[5], lys[5];
        lxs[0] = __fadd_rn(-s2, px); lxs[1] = __fadd_rn(-s, px); lxs[2] = px;
        lxs[3] = __fadd_rn( s, px);  lxs[4] = __fadd_rn(s2, px);
        lys[0] = __fadd_rn(-s2, py); lys[1] = __fadd_rn(-s, py); lys[2] = py;
        lys[3] = __fadd_rn( s, py);  lys[4] = __fadd_rn(s2, py);

        const unsigned j = 2 * w;
        const float4 a0 = filt[j];
        const float4 a1 = filt[j + 1];

        int aux = 0, alx = 0, auy = 0, aly = 0;
        float4 o;
        cell(a0, psum, lxs, lys, o.x, o.y, aux, alx, auy, aly);
        cell(a1, psum, lxs, lys, o.z, o.w, aux, alx, auy, aly);
        *reinterpret_cast<float4*>(d_out + G0_BASE + 4 * (size_t)q) = o;

        // Per-row any() flags. Fast path: wave entirely within one row
        // (47/48 of iterations) -> one atomicOr by lane 0.
        int bits = aux | (alx << 1) | (auy << 2) | (aly << 3);
        if (__any(bits)) {
            const unsigned rid0 = (unsigned)__shfl((int)rid, 0);
            if (__all(rid == rid0)) {
                int f0 = __any(aux) ? 1 : 0;
                int f1 = __any(alx) ? 1 : 0;
                int f2 = __any(auy) ? 1 : 0;
                int f3 = __any(aly) ? 1 : 0;
                if ((threadIdx.x & 63) == 0)
                    atomicOr(&flags[rid0], f0 | (f1 << 1) | (f2 << 2) | (f3 << 3));
            } else if (bits) {
                atomicOr(&flags[rid], bits);
            }
        }
    }
}

// ---------------------------------------------------------------------------
// Kernel 3: flags -> Gc. Gc index is 2*rid by layout.
// ---------------------------------------------------------------------------
__global__ void gc_kernel(const int* __restrict__ flags,
                          float* __restrict__ d_out) {
    int rid = blockIdx.x * blockDim.x + threadIdx.x;
    if (rid >= NROWS) return;
    int f = flags[rid];
    float cx = (f & 1) ? -1.0f : ((f & 2) ? 1.0f : 0.0f);
    float cy = (f & 4) ? -1.0f : ((f & 8) ? 1.0f : 0.0f);
    d_out[GC0_BASE + 2 * (size_t)rid]     = cx;
    d_out[GC0_BASE + 2 * (size_t)rid + 1] = cy;
}

// ---------------------------------------------------------------------------
extern "C" void kernel_launch(void* const* d_in, const int* in_sizes, int n_in,
                              void* d_out, int out_size, void* d_ws, size_t ws_size,
                              hipStream_t stream) {
    const float* f_v        = (const float*)d_in[0];
    const int*   edges      = (const int*)d_in[1];
    const float* bars0      = (const float*)d_in[2];
    const float* bars1      = (const float*)d_in[3];
    const float* sample_pts = (const float*)d_in[4];
    float* out = (float*)d_out;

    float4* filt  = (float4*)d_ws;              // 6000 * 16 B = 96 KB
    int*    flags = (int*)d_ws + S * 4;         // 15000 ints after filt

    // bars0 / bars1 pass through to output.
    (void)hipMemcpyAsync(out,         bars0, (size_t)P * R * sizeof(float),
                         hipMemcpyDeviceToDevice, stream);
    (void)hipMemcpyAsync(out + P * R, bars1, (size_t)P * R * sizeof(float),
                         hipMemcpyDeviceToDevice, stream);

    build_filt_kernel<<<(NROWS + 255) / 256, 256, 0, stream>>>(f_v, edges,
                                                               filt, flags);

    grad_kernel<<<dim3(NBLK), BS, 0, stream>>>(filt, bars0, bars1,
                                               sample_pts, out, flags);

    gc_kernel<<<(NROWS + 255) / 256, 256, 0, stream>>>(flags, out);
}

// Round 9
// 762.603 us; speedup vs baseline: 1.0680x; 1.0680x over previous
//
#include <hip/hip_runtime.h>

// Problem constants (match reference setup_inputs / module constants)
#define EPS_F      1e-4f
#define GRID_RES_F 0.01f
#define ATOL_F     0.01f
#define RTOL_F     1e-5f

static constexpr int V = 1200;
static constexpr int E = 4800;
static constexpr int S = V + E;      // 6000 filtration points
static constexpr int P = 2500;
static constexpr int R = 3;

// Output layout (flat fp32, return order):
//   bars0: [0, 7500)   bars1: [7500, 15000)
//   G0: (R,P,2S) at 15000   G1: follows   Gc0: (R,P,2)   Gc1: follows
static constexpr size_t G0_BASE      = 15000ull;
static constexpr size_t ROW_LEN      = 2ull * S;            // 12000 floats per G row
static constexpr size_t COMBO_STRIDE = (size_t)P * ROW_LEN; // 30,000,000 floats per (b,r) slab
static constexpr size_t G_ELEMS      = (size_t)R * COMBO_STRIDE; // 90,000,000
static constexpr size_t GC0_BASE     = G0_BASE + 2 * G_ELEMS;    // 180,015,000

// ---------------------------------------------------------------------------
// Kernel 1: build filtration table. filt[j] = (fx, fy, tol_x, tol_y)
// ---------------------------------------------------------------------------
__global__ void build_filt_kernel(const float* __restrict__ f_v,
                                  const int*   __restrict__ edges,
                                  float4*      __restrict__ filt) {
    int j = blockIdx.x * blockDim.x + threadIdx.x;
    if (j >= S) return;
    float fx, fy;
    if (j < V) {
        fx = f_v[2 * j];
        fy = f_v[2 * j + 1];
    } else {
        int e = j - V;
        int a = edges[2 * e];
        int b = edges[2 * e + 1];
        fx = __fadd_rn(fmaxf(f_v[2 * a],     f_v[2 * b]),     EPS_F);
        fy = __fadd_rn(fmaxf(f_v[2 * a + 1], f_v[2 * b + 1]), EPS_F);
    }
    // tol = ATOL + RTOL*|f| with NumPy per-op rounding (no fma contraction).
    float tolx = __fadd_rn(ATOL_F, __fmul_rn(RTOL_F, fabsf(fx)));
    float toly = __fadd_rn(ATOL_F, __fmul_rn(RTOL_F, fabsf(fy)));
    filt[j] = make_float4(fx, fy, tolx, toly);
}

// ---------------------------------------------------------------------------
// min_k |l[k] - f| ; comparing vs tol is bit-exact-equivalent to
// any_k(|l[k]-f| <= tol) — min/cmp involve no rounding. Subs keep ref rounding.
// (Field-proven: absmax 0.0.)
// ---------------------------------------------------------------------------
__device__ __forceinline__ float mindist(const float* l, float f) {
    float a = fabsf(__fsub_rn(l[0], f));
    float b = fabsf(__fsub_rn(l[1], f));
    float c = fabsf(__fsub_rn(l[2], f));
    float d = fabsf(__fsub_rn(l[3], f));
    float e = fabsf(__fsub_rn(l[4], f));
    return fminf(fminf(fminf(a, b), fminf(c, d)), e);  // -> v_min3 pairs
}

// Per-cell evaluation for one (b,r) combo; flag bits accumulate into 6-bit masks.
__device__ __forceinline__ void cell(const float4& f, float psum,
                                     const float* lxs, const float* lys,
                                     float& vx, float& vy, int bit,
                                     int& aux, int& alx, int& auy, int& aly) {
    float fsum = __fadd_rn(f.x, f.y);
    bool ab = fsum > psum, be = fsum < psum;
    float sg = ab ? 1.0f : (be ? -1.0f : 0.0f);
    bool cx = (mindist(lxs, f.x) <= f.z) && (f.y <= lys[4]);
    bool cy = (mindist(lys, f.y) <= f.w) && (f.x <= lxs[4]);
    vx = cx ? sg : 0.0f;   // vx = ux - lx == condx ? (above - below) : 0
    vy = cy ? sg : 0.0f;
    if (cx && ab) aux |= bit;
    if (cx && be) alx |= bit;
    if (cy && ab) auy |= bit;
    if (cy && be) aly |= bit;
}

// ---------------------------------------------------------------------------
// Kernel 2: ONE block per sample point p, all 6 (bar-set, r) rows — the
// fused+CACHED cell of the experiment matrix (R2 tested fused+NT; NT itself
// costs +50us, measured twice). Theory under test: per-CU vmem INSTRUCTION
// throughput is the limiter (all 5 store-address-pattern theories are
// measured null, R2-R8). Fusion cuts filt-load instructions 6x:
// 6 -> 1.33 vmem wave-instrs per KB written (-56%).
//   - 256 threads, 2 cells/thread/iter, register prefetch (R1-proven loop)
//   - line arrays hoisted (loop-invariant), fully static indexing
//   - plain cached float4 stores (NOT nontemporal)
// Numerics bit-identical (same cell()); fused indexing/Gc layout
// field-verified by R2's absmax 0.0 pass.
// ---------------------------------------------------------------------------
__global__ __launch_bounds__(256) void grad_kernel(
        const float4* __restrict__ filt,
        const float*  __restrict__ bars0,
        const float*  __restrict__ bars1,
        const float*  __restrict__ sample_pts,
        float*        __restrict__ d_out) {
    const int p = blockIdx.x;   // 0..P-1

    const float px = sample_pts[2 * p];
    const float py = sample_pts[2 * p + 1];
    const float psum = __fadd_rn(px, py);

    // Per-combo line arrays, hoisted (combo c = 3*b + r).
    float lxs[6][5], lys[6][5];
#pragma unroll
    for (int c = 0; c < 6; ++c) {
        const float* bar = (c < 3) ? bars0 : bars1;
        const int r = (c < 3) ? c : c - 3;
        const float s  = __fadd_rn(bar[p * R + r], GRID_RES_F);
        const float s2 = __fmul_rn(2.0f, s);   // exact (x2)
        lxs[c][0] = __fadd_rn(-s2, px); lxs[c][1] = __fadd_rn(-s, px);
        lxs[c][2] = px;
        lxs[c][3] = __fadd_rn( s, px);  lxs[c][4] = __fadd_rn( s2, px);
        lys[c][0] = __fadd_rn(-s2, py); lys[c][1] = __fadd_rn(-s, py);
        lys[c][2] = py;
        lys[c][3] = __fadd_rn( s, py);  lys[c][4] = __fadd_rn( s2, py);
    }

    float* gbase = d_out + G0_BASE + (size_t)p * ROW_LEN;

    __shared__ int shf[24];   // [0..5]=ux, [6..11]=lx, [12..17]=uy, [18..23]=ly
    if (threadIdx.x < 24) shf[threadIdx.x] = 0;
    __syncthreads();

    int aux = 0, alx = 0, auy = 0, aly = 0;   // 6-bit masks, bit c per combo

    // 2 cells per thread per iteration; 256 threads -> 512 cells per sweep.
    int j = threadIdx.x * 2;
    float4 a0, a1;
    if (j < S) { a0 = filt[j]; a1 = filt[j + 1]; }
    while (j < S) {
        const int jn = j + 512;
        float4 b0, b1;
        if (jn < S) {   // prefetch next iteration's cells before compute/store
            b0 = filt[jn]; b1 = filt[jn + 1];
        }
#pragma unroll
        for (int c = 0; c < 6; ++c) {
            const int bit = 1 << c;
            float4 o;
            cell(a0, psum, lxs[c], lys[c], o.x, o.y, bit, aux, alx, auy, aly);
            cell(a1, psum, lxs[c], lys[c], o.z, o.w, bit, aux, alx, auy, aly);
            *reinterpret_cast<float4*>(
                gbase + (size_t)c * COMBO_STRIDE + 2 * (size_t)j) = o;
        }
        a0 = b0; a1 = b1;
        j = jn;
    }

    // Row-wide any() flags: benign-race shared writes (all writers store 1).
#pragma unroll
    for (int c = 0; c < 6; ++c) {
        if (aux & (1 << c)) shf[c]      = 1;
        if (alx & (1 << c)) shf[6 + c]  = 1;
        if (auy & (1 << c)) shf[12 + c] = 1;
        if (aly & (1 << c)) shf[18 + c] = 1;
    }
    __syncthreads();

    if (threadIdx.x < 6) {
        const int c = threadIdx.x;
        float cx = shf[c]      ? -1.0f : (shf[6 + c]  ? 1.0f : 0.0f);
        float cy = shf[12 + c] ? -1.0f : (shf[18 + c] ? 1.0f : 0.0f);
        // Gc(b,r,p,2): GC0_BASE + b*R*P*2 + (r*P+p)*2
        size_t gc = GC0_BASE + (size_t)c * ((size_t)P * 2) + (size_t)p * 2;
        d_out[gc]     = cx;
        d_out[gc + 1] = cy;
    }
}

// ---------------------------------------------------------------------------
extern "C" void kernel_launch(void* const* d_in, const int* in_sizes, int n_in,
                              void* d_out, int out_size, void* d_ws, size_t ws_size,
                              hipStream_t stream) {
    const float* f_v        = (const float*)d_in[0];
    const int*   edges      = (const int*)d_in[1];
    const float* bars0      = (const float*)d_in[2];
    const float* bars1      = (const float*)d_in[3];
    const float* sample_pts = (const float*)d_in[4];
    float* out = (float*)d_out;

    float4* filt = (float4*)d_ws;   // S * 16 B = 96 KB scratch

    // bars0 / bars1 pass through to output.
    (void)hipMemcpyAsync(out,         bars0, (size_t)P * R * sizeof(float),
                         hipMemcpyDeviceToDevice, stream);
    (void)hipMemcpyAsync(out + P * R, bars1, (size_t)P * R * sizeof(float),
                         hipMemcpyDeviceToDevice, stream);

    build_filt_kernel<<<(S + 255) / 256, 256, 0, stream>>>(f_v, edges, filt);

    grad_kernel<<<dim3(P), 256, 0, stream>>>(filt, bars0, bars1,
                                             sample_pts, out);
}

// Round 10
// 723.677 us; speedup vs baseline: 1.1254x; 1.0538x over previous
//
#include <hip/hip_runtime.h>

// Problem constants (match reference setup_inputs / module constants)
#define EPS_F      1e-4f
#define GRID_RES_F 0.01f
#define ATOL_F     0.01f
#define RTOL_F     1e-5f

static constexpr int V = 1200;
static constexpr int E = 4800;
static constexpr int S = V + E;      // 6000 filtration points
static constexpr int P = 2500;
static constexpr int R = 3;

static constexpr int NROWS = 2 * R * P;          // 15000 G rows, address-ordered
static constexpr int NXCD  = 8;
static constexpr int ROWS_PER_XCD = NROWS / NXCD; // 1875 exactly

// Output layout (flat fp32, return order):
//   bars0: [0, 7500)   bars1: [7500, 15000)
//   G0: (R,P,2S) at 15000   G1: follows   Gc0: (R,P,2)   Gc1: follows
static constexpr size_t G0_BASE  = 15000ull;
static constexpr size_t ROW_LEN  = 2ull * S;                 // 12000 floats per G row
static constexpr size_t G_ELEMS  = (size_t)R * P * ROW_LEN;  // 90,000,000
static constexpr size_t GC0_BASE = G0_BASE + 2 * G_ELEMS;    // 180,015,000

// ---------------------------------------------------------------------------
// Kernel 1: build filtration table. filt[j] = (fx, fy, tol_x, tol_y)
// ---------------------------------------------------------------------------
__global__ void build_filt_kernel(const float* __restrict__ f_v,
                                  const int*   __restrict__ edges,
                                  float4*      __restrict__ filt) {
    int j = blockIdx.x * blockDim.x + threadIdx.x;
    if (j >= S) return;
    float fx, fy;
    if (j < V) {
        fx = f_v[2 * j];
        fy = f_v[2 * j + 1];
    } else {
        int e = j - V;
        int a = edges[2 * e];
        int b = edges[2 * e + 1];
        fx = __fadd_rn(fmaxf(f_v[2 * a],     f_v[2 * b]),     EPS_F);
        fy = __fadd_rn(fmaxf(f_v[2 * a + 1], f_v[2 * b + 1]), EPS_F);
    }
    // tol = ATOL + RTOL*|f| with NumPy per-op rounding (no fma contraction).
    float tolx = __fadd_rn(ATOL_F, __fmul_rn(RTOL_F, fabsf(fx)));
    float toly = __fadd_rn(ATOL_F, __fmul_rn(RTOL_F, fabsf(fy)));
    filt[j] = make_float4(fx, fy, tolx, toly);
}

// ---------------------------------------------------------------------------
// min_k |l[k] - f| ; comparing vs tol is bit-exact-equivalent to
// any_k(|l[k]-f| <= tol) — min/cmp involve no rounding. Subs keep ref rounding.
// (Field-proven: absmax 0.0.)
// ---------------------------------------------------------------------------
__device__ __forceinline__ float mindist(const float* l, float f) {
    float a = fabsf(__fsub_rn(l[0], f));
    float b = fabsf(__fsub_rn(l[1], f));
    float c = fabsf(__fsub_rn(l[2], f));
    float d = fabsf(__fsub_rn(l[3], f));
    float e = fabsf(__fsub_rn(l[4], f));
    return fminf(fminf(fminf(a, b), fminf(c, d)), e);  // -> v_min3 pairs
}

__device__ __forceinline__ void cell(const float4& f, float psum,
                                     const float* lxs, const float* lys,
                                     float& vx, float& vy,
                                     int& aux, int& alx, int& auy, int& aly) {
    float fsum = __fadd_rn(f.x, f.y);
    bool ab = fsum > psum, be = fsum < psum;
    float sg = ab ? 1.0f : (be ? -1.0f : 0.0f);
    bool cx = (mindist(lxs, f.x) <= f.z) && (f.y <= lys[4]);
    bool cy = (mindist(lys, f.y) <= f.w) && (f.x <= lxs[4]);
    vx = cx ? sg : 0.0f;   // vx = ux - lx == condx ? (above - below) : 0
    vy = cy ? sg : 0.0f;
    aux |= (int)(cx && ab); alx |= (int)(cx && be);
    auy |= (int)(cy && ab); aly |= (int)(cy && be);
}

// ---------------------------------------------------------------------------
// Kernel 2: CHAMPION (R6, 721.5us). R1-proven single-stream inner loop
// (4 cells/thread, register prefetch, half-density cached dwordx4 stores)
// + cost-free bijective XCD-contiguous row remap. Six store-path mechanisms
// measured null/harmful against this structure (R2-R9): stream length, L2
// bypass (NT +50 twice), XCD window clustering, line-fill density, single
// dense front, row fusion / load-traffic cut. grad ~262us vs 114us pure-write
// floor is the empirical mixed-kernel write ceiling for this shape.
// ---------------------------------------------------------------------------
__global__ __launch_bounds__(256) void grad_kernel(
        const float4* __restrict__ filt,
        const float*  __restrict__ bars0,
        const float*  __restrict__ bars1,
        const float*  __restrict__ sample_pts,
        float*        __restrict__ d_out) {
    // XCD-contiguous bijective remap (15000 = 8 * 1875 exactly).
    const int i     = blockIdx.x;
    const int rid   = (i & (NXCD - 1)) * ROWS_PER_XCD + (i >> 3);
    // Address-ordered row id -> (b, r, p):  rid = b*(R*P) + r*P + p
    const int b   = rid / (R * P);
    const int rem = rid - b * (R * P);
    const int r   = rem / P;
    const int p   = rem - r * P;

    const float* bar = (b == 0) ? bars0 : bars1;
    const float px = sample_pts[2 * p];
    const float py = sample_pts[2 * p + 1];
    const float psum = __fadd_rn(px, py);
    const float s  = __fadd_rn(bar[p * R + r], GRID_RES_F);
    const float s2 = __fmul_rn(2.0f, s);   // exact (x2)

    float lxs[5], lys[5];
    lxs[0] = __fadd_rn(-s2, px); lxs[1] = __fadd_rn(-s, px); lxs[2] = px;
    lxs[3] = __fadd_rn( s, px);  lxs[4] = __fadd_rn(s2, px);
    lys[0] = __fadd_rn(-s2, py); lys[1] = __fadd_rn(-s, py); lys[2] = py;
    lys[3] = __fadd_rn( s, py);  lys[4] = __fadd_rn(s2, py);

    float* Grow = d_out + G0_BASE + (size_t)rid * ROW_LEN;

    __shared__ int sh_flags[4];
    if (threadIdx.x < 4) sh_flags[threadIdx.x] = 0;
    __syncthreads();

    int aux = 0, alx = 0, auy = 0, aly = 0;

    // 4 cells per thread per iteration; stride 1024 cells per block sweep.
    int j = threadIdx.x * 4;
    float4 a0, a1, a2, a3;
    if (j < S) { a0 = filt[j]; a1 = filt[j+1]; a2 = filt[j+2]; a3 = filt[j+3]; }
    while (j < S) {
        const int jn = j + 1024;
        float4 b0, b1, b2, b3;
        if (jn < S) {  // prefetch next iteration's cells before compute/store
            b0 = filt[jn]; b1 = filt[jn+1]; b2 = filt[jn+2]; b3 = filt[jn+3];
        }
        float4 o0, o1;
        cell(a0, psum, lxs, lys, o0.x, o0.y, aux, alx, auy, aly);
        cell(a1, psum, lxs, lys, o0.z, o0.w, aux, alx, auy, aly);
        cell(a2, psum, lxs, lys, o1.x, o1.y, aux, alx, auy, aly);
        cell(a3, psum, lxs, lys, o1.z, o1.w, aux, alx, auy, aly);
        float4* dst = reinterpret_cast<float4*>(Grow + 2 * j);
        dst[0] = o0;
        dst[1] = o1;
        a0 = b0; a1 = b1; a2 = b2; a3 = b3;
        j = jn;
    }

    // Row-wide any() flags: benign-race shared writes (all writers store 1).
    if (aux) sh_flags[0] = 1;
    if (alx) sh_flags[1] = 1;
    if (auy) sh_flags[2] = 1;
    if (aly) sh_flags[3] = 1;
    __syncthreads();

    if (threadIdx.x == 0) {
        float cx = sh_flags[0] ? -1.0f : (sh_flags[1] ? 1.0f : 0.0f);
        float cy = sh_flags[2] ? -1.0f : (sh_flags[3] ? 1.0f : 0.0f);
        size_t gc = GC0_BASE + (size_t)b * ((size_t)R * P * 2)
                             + ((size_t)(r * P + p)) * 2;
        d_out[gc]     = cx;
        d_out[gc + 1] = cy;
    }
}

// ---------------------------------------------------------------------------
extern "C" void kernel_launch(void* const* d_in, const int* in_sizes, int n_in,
                              void* d_out, int out_size, void* d_ws, size_t ws_size,
                              hipStream_t stream) {
    const float* f_v        = (const float*)d_in[0];
    const int*   edges      = (const int*)d_in[1];
    const float* bars0      = (const float*)d_in[2];
    const float* bars1      = (const float*)d_in[3];
    const float* sample_pts = (const float*)d_in[4];
    float* out = (float*)d_out;

    float4* filt = (float4*)d_ws;   // S * 16 B = 96 KB scratch

    // bars0 / bars1 pass through to output.
    (void)hipMemcpyAsync(out,         bars0, (size_t)P * R * sizeof(float),
                         hipMemcpyDeviceToDevice, stream);
    (void)hipMemcpyAsync(out + P * R, bars1, (size_t)P * R * sizeof(float),
                         hipMemcpyDeviceToDevice, stream);

    build_filt_kernel<<<(S + 255) / 256, 256, 0, stream>>>(f_v, edges, filt);

    grad_kernel<<<dim3(NROWS), 256, 0, stream>>>(filt, bars0, bars1,
                                                 sample_pts, out);
}